// Round 3
// baseline (3985.009 us; speedup 1.0000x reference)
//
#include <hip/hip_runtime.h>
#include <stdint.h>

typedef unsigned short u16;
typedef unsigned int   u32;
typedef __attribute__((ext_vector_type(8))) short short8;
typedef __attribute__((ext_vector_type(4))) float f32x4;

#define CAP   52
#define NSWEEP 48

__device__ __forceinline__ u16 rne_bf16(float f){
  u32 u = __float_as_uint(f);
  u32 r = (u + 0x7fffu + ((u >> 16) & 1u)) >> 16;
  return (u16)r;
}
__device__ __forceinline__ float bf16_to_f(u16 h){
  return __uint_as_float(((u32)h) << 16);
}
__device__ __forceinline__ float tanh_fast(float x){
  float e = __expf(2.0f * x);
  return 1.0f - 2.0f / (e + 1.0f);
}

// ---------------------------------------------------------------------------
// A-pack: [xhi fbhi | xlo fblo], row m = b*1024+s, K=2048 bf16 bits
// ---------------------------------------------------------------------------
__global__ __launch_bounds__(256) void pack_a_k(const float* __restrict__ x,
                                                const float* __restrict__ fb,
                                                u16* __restrict__ A){
  int idx = blockIdx.x * 256 + threadIdx.x;          // 16384*512
  int m = idx >> 9, d = idx & 511;
  float xv = x[idx];
  float fv = fb[idx];
  u16 xh = rne_bf16(xv); u16 xl = rne_bf16(xv - bf16_to_f(xh));
  u16 fh = rne_bf16(fv); u16 fl = rne_bf16(fv - bf16_to_f(fh));
  size_t base = (size_t)m * 2048;
  A[base + d]        = xh;
  A[base + 512 + d]  = fh;
  A[base + 1024 + d] = xl;
  A[base + 1536 + d] = fl;
}

// ---------------------------------------------------------------------------
// B-pack with ROW PERMUTATION (row n of packed B = original row rowperm[n]).
// K=3072: [Winhi Wfbhi | Winhi Wfbhi | Winlo Wfblo]
// ---------------------------------------------------------------------------
__global__ __launch_bounds__(256) void pack_b_k(const float* __restrict__ Win,
                                                const float* __restrict__ Wfb,
                                                const int* __restrict__ rowperm,
                                                u16* __restrict__ Bm){
  int idx = blockIdx.x * 256 + threadIdx.x;          // 2048*512
  int n = idx >> 9, d = idx & 511;
  int row = rowperm[n];
  float iv = Win[(size_t)row * 512 + d];
  float fv = Wfb[(size_t)row * 512 + d];
  u16 ih = rne_bf16(iv); u16 il = rne_bf16(iv - bf16_to_f(ih));
  u16 fh = rne_bf16(fv); u16 fl = rne_bf16(fv - bf16_to_f(fh));
  size_t base = (size_t)n * 3072;
  Bm[base + d]        = ih;
  Bm[base + 512 + d]  = fh;
  Bm[base + 1024 + d] = ih;
  Bm[base + 1536 + d] = fh;
  Bm[base + 2048 + d] = il;
  Bm[base + 2560 + d] = fl;
}

// ---------------------------------------------------------------------------
// Drive GEMM: M=16384,N=2048,K=3072, 128x128 tile, plain coalesced stores.
// ---------------------------------------------------------------------------
#define GLDS(gp, lp) __builtin_amdgcn_global_load_lds( \
    (const __attribute__((address_space(1))) void*)(gp), \
    (__attribute__((address_space(3))) void*)(lp), 16, 0, 0)

__global__ __launch_bounds__(256) void gemm_k(const u16* __restrict__ A,
                                              const u16* __restrict__ Bm,
                                              float* __restrict__ C){
  __shared__ __align__(16) u16 As[128 * 32];
  __shared__ __align__(16) u16 Bs[128 * 32];
  const int tid = threadIdx.x;
  const int w = tid >> 6, l = tid & 63;
  const int bid = blockIdx.x;
  const int mt = bid >> 4, nt = bid & 15;
  const int m0 = mt * 128, n0 = nt * 128;
  const int srow = tid >> 2;
  const int scol = (tid & 3) * 8;
  const int wr = w & 1, wc = w >> 1;
  const int lhi = l >> 4, llo = l & 15;

  f32x4 acc[4][4];
  #pragma unroll
  for (int i = 0; i < 4; i++)
    #pragma unroll
    for (int j = 0; j < 4; j++)
      acc[i][j] = (f32x4){0.f, 0.f, 0.f, 0.f};

  for (int kt = 0; kt < 96; ++kt){
    int k = kt * 32;
    int keff = (k >= 2048) ? (k - 2048) : k;
    #pragma unroll
    for (int r = 0; r < 2; r++){
      const u16* ga = A  + (size_t)(m0 + r * 64 + srow) * 2048 + keff + scol;
      GLDS(ga, &As[r * 2048 + w * 512]);
      const u16* gb = Bm + (size_t)(n0 + r * 64 + srow) * 3072 + k + scol;
      GLDS(gb, &Bs[r * 2048 + w * 512]);
    }
    __syncthreads();
    short8 af[4], bf[4];
    #pragma unroll
    for (int i = 0; i < 4; i++){
      af[i] = *(const short8*)&As[(wr * 64 + i * 16 + llo) * 32 + lhi * 8];
      bf[i] = *(const short8*)&Bs[(wc * 64 + i * 16 + llo) * 32 + lhi * 8];
    }
    #pragma unroll
    for (int i = 0; i < 4; i++)
      #pragma unroll
      for (int j = 0; j < 4; j++)
        acc[i][j] = __builtin_amdgcn_mfma_f32_16x16x32_bf16(af[i], bf[j], acc[i][j], 0, 0, 0);
    __syncthreads();
  }
  #pragma unroll
  for (int i = 0; i < 4; i++)
    #pragma unroll
    for (int j = 0; j < 4; j++)
      #pragma unroll
      for (int rg = 0; rg < 4; rg++){
        int mr = m0 + wr * 64 + i * 16 + lhi * 4 + rg;
        int nc = n0 + wc * 64 + j * 16 + llo;
        C[(size_t)mr * 2048 + nc] = acc[i][j][rg];
      }
}

// ---------------------------------------------------------------------------
// count nnz per row (one wave per row)
// ---------------------------------------------------------------------------
__global__ __launch_bounds__(256) void count_k(const float* __restrict__ W,
                                               int* __restrict__ nnz){
  int gt = blockIdx.x * 256 + threadIdx.x;
  int row = gt >> 6, l = gt & 63;
  const float* wr = W + (size_t)row * 2048;
  int c = 0;
  for (int i = 0; i < 32; i++) c += (wr[i * 64 + l] != 0.0f) ? 1 : 0;
  for (int off = 32; off; off >>= 1) c += __shfl_down(c, off, 64);
  if (l == 0) nnz[row] = c;
}

// ---------------------------------------------------------------------------
// Counting-sort rows desc by nnz, pair p <-> 2047-p; emit rowperm for pack_b.
// ---------------------------------------------------------------------------
__global__ __launch_bounds__(1024) void sort_k(const int* __restrict__ nnz,
                                               u32* __restrict__ rowsp,
                                               int* __restrict__ L1a,
                                               int* __restrict__ rowperm){
  __shared__ int hist[64], off[64], cur[64];
  __shared__ int order[2048];
  int tid = threadIdx.x;
  if (tid < 64){ hist[tid] = 0; cur[tid] = 0; }
  __syncthreads();
  for (int r = tid; r < 2048; r += 1024){
    int b = nnz[r]; if (b > 63) b = 63;
    atomicAdd(&hist[b], 1);
  }
  __syncthreads();
  if (tid == 0){
    int run = 0;
    for (int b = 63; b >= 0; b--){ off[b] = run; run += hist[b]; }
  }
  __syncthreads();
  for (int r = tid; r < 2048; r += 1024){
    int b = nnz[r]; if (b > 63) b = 63;
    int pos = off[b] + atomicAdd(&cur[b], 1);
    order[pos] = r;
  }
  __syncthreads();
  int rA = order[tid], rB = order[2047 - tid];
  rowsp[tid] = (u32)rA | ((u32)rB << 16);
  L1a[tid] = nnz[rA];
  rowperm[tid] = rA;
  rowperm[tid + 1024] = rB;
}

// ---------------------------------------------------------------------------
// Fill per-thread item words (slot-major): [0,L1)=rowA, [L1,..)=rowB, pad 0.
// COMPENSATED ENCODING: word w has low 13 bits = byte addr (col*4), and
// float(w) approximates the true weight within +/-0x1000 bit positions:
//   w = ((bits(v) - addr + 0x1000) & 0xFFFFE000) + addr
// rnn uses float(w) DIRECTLY (no value-mask AND in the hot loop).
// ---------------------------------------------------------------------------
__global__ __launch_bounds__(256) void fill_k(const float* __restrict__ W,
                                              const u32* __restrict__ rowsp,
                                              u32* __restrict__ wpk){
  int gt = blockIdx.x * 256 + threadIdx.x;
  int p = gt >> 6, l = gt & 63;
  u32 rp = rowsp[p];
  int rA = (int)(rp & 0xffffu), rB = (int)(rp >> 16);
  int base = 0;
  for (int h = 0; h < 2; h++){
    int row = h ? rB : rA;
    const float* wr = W + (size_t)row * 2048;
    int cnt = 0;
    for (int i = 0; i < 32; i++){
      int c = i * 64 + l;
      float v = wr[c];
      unsigned long long m = __ballot(v != 0.0f);
      int pre = __popcll(m & ((1ull << l) - 1ull));
      if (v != 0.0f){
        int s = base + cnt + pre;
        if (s < CAP){
          u32 addr = (u32)c << 2;                    // byte offset, bits 12:2
          u32 u = __float_as_uint(v);
          u = ((u - addr + 0x1000u) & 0xFFFFE000u) + addr;
          wpk[s * 1024 + p] = u;
        }
      }
      cnt += __popcll(m);
    }
    base += cnt;
  }
  for (int s = base + l; s < CAP; s += 64)
    wpk[s * 1024 + p] = 0u;                          // pad; sched_k retargets
}

// ---------------------------------------------------------------------------
// BANK SCHEDULER v2 (in-place on wpk). One 64-lane wave per rnn wave.
// Phase 1: greedy capacity-2 claiming (round-2 algorithm, barrier-free).
// Phase 2: ITERATIVE REPAIR toward the Konig edge-coloring solution: each
//   lane swaps items between two of its OWN slots (same segment -> rnn
//   semantics preserved) when this strictly drains an overfull (slot,bank)
//   cell; pads retarget banks in place. Optimistic atomic claims on a
//   persistent cnt[slot][bank] table; stale non-atomic pre-checks are safe
//   (claims are authoritative). Single wave => no barriers anywhere.
// ---------------------------------------------------------------------------
__global__ __launch_bounds__(64) void sched_k(u32* wpk,
                                              const u32* __restrict__ rowsp,
                                              const int* __restrict__ nnz){
  __shared__ u32 pool[CAP * 64];                     // unassigned items
  __shared__ u32 itm[CAP * 64];                      // itm[s*64+lane]
  __shared__ int cnt[CAP * 32];                      // loads per (slot,bank)
  const int lane = threadIdx.x;
  const int p = blockIdx.x * 64 + lane;
  u32 rp = rowsp[p];
  int rA = (int)(rp & 0xffffu), rB = (int)(rp >> 16);
  int L1 = nnz[rA]; if (L1 > CAP) L1 = CAP;
  int nT = L1 + nnz[rB]; if (nT > CAP) nT = CAP;

  for (int i = lane; i < CAP * 32; i += 64) cnt[i] = 0;
  for (int k = 0; k < CAP; k++) pool[k * 64 + lane] = wpk[k * 1024 + p];
  __builtin_amdgcn_s_waitcnt(0);                     // single wave: lockstep

  // ---- Phase 1: greedy ----
  unsigned long long used = 0ull;
  for (int s = 0; s < CAP; s++){
    int* c = &cnt[s * 32];
    u32 word;
    if (s < nT){
      int lo = (s < L1) ? 0 : L1;
      int hi = (s < L1) ? L1 : nT;
      int chosen = -1;
      for (int capc = 2; chosen < 0; capc++){
        for (int j = lo; j < hi; j++){
          if (used & (1ull << j)) continue;
          u32 w = pool[j * 64 + lane];
          int bk = (int)((w >> 2) & 31u);
          int old = atomicAdd(&c[bk], 1);
          if (old < capc){ chosen = j; break; }
          atomicSub(&c[bk], 1);
        }
      }
      used |= 1ull << chosen;
      word = pool[chosen * 64 + lane];
    } else {
      int bsel = -1;
      for (int capc = 2; bsel < 0; capc++){
        for (int bk0 = 0; bk0 < 32; bk0++){
          int bk = (bk0 + lane) & 31;
          int old = atomicAdd(&c[bk], 1);
          if (old < capc){ bsel = bk; break; }
          atomicSub(&c[bk], 1);
        }
      }
      word = (u32)bsel << 2;                         // pad -> denormal ~ 0
    }
    itm[s * 64 + lane] = word;
  }

  // ---- Phase 2: repair sweeps ----
  for (int sweep = 0; sweep < NSWEEP; sweep++){
    int fixes = 0;
    for (int s1 = 0; s1 < CAP; s1++){
      u32 w1 = itm[s1 * 64 + lane];
      int b1 = (int)((w1 >> 2) & 31u);
      if (cnt[s1 * 32 + b1] <= 2) continue;          // not overfull (stale ok)
      if (s1 >= nT){                                 // pad: retarget in place
        for (int bk0 = 1; bk0 < 32; bk0++){
          int b2 = (b1 + bk0 + lane) & 31;
          int old = atomicAdd(&cnt[s1 * 32 + b2], 1);
          if (old < 2){
            atomicSub(&cnt[s1 * 32 + b1], 1);
            itm[s1 * 64 + lane] = (u32)b2 << 2;
            fixes++; break;
          }
          atomicSub(&cnt[s1 * 32 + b2], 1);
        }
        continue;
      }
      int lo = (s1 < L1) ? 0 : L1;
      int hi = (s1 < L1) ? L1 : nT;
      int len = hi - lo;
      if (len < 2) continue;
      for (int d = 1; d < len; d++){
        int s2 = lo + ((s1 - lo) + d + lane + sweep * 7) % len;
        if (s2 == s1) continue;
        u32 w2 = itm[s2 * 64 + lane];
        int b2 = (int)((w2 >> 2) & 31u);
        if (b1 == b2) continue;
        if (cnt[s2 * 32 + b1] >= 2) continue;        // pre-check (stale ok)
        if (cnt[s1 * 32 + b2] >= 2) continue;
        int a = atomicSub(&cnt[s1 * 32 + b1], 1);    // claim drain
        if (a <= 2){ atomicAdd(&cnt[s1 * 32 + b1], 1); break; } // already fixed
        int c2 = atomicAdd(&cnt[s1 * 32 + b2], 1);
        if (c2 >= 2){
          atomicSub(&cnt[s1 * 32 + b2], 1);
          atomicAdd(&cnt[s1 * 32 + b1], 1); continue;
        }
        int c3 = atomicAdd(&cnt[s2 * 32 + b1], 1);
        if (c3 >= 2){
          atomicSub(&cnt[s2 * 32 + b1], 1);
          atomicSub(&cnt[s1 * 32 + b2], 1);
          atomicAdd(&cnt[s1 * 32 + b1], 1); continue;
        }
        atomicSub(&cnt[s2 * 32 + b2], 1);
        itm[s1 * 64 + lane] = w2;
        itm[s2 * 64 + lane] = w1;
        fixes++; break;
      }
    }
    if (__ballot(fixes != 0) == 0ull) break;         // converged / stuck
  }

  for (int s = 0; s < CAP; s++)
    wpk[s * 1024 + p] = itm[s * 64 + lane];
}

// ---------------------------------------------------------------------------
// Recurrent kernel (unchanged from round 2): 16 WGs, 1024 thr, state in LDS,
// 52 packed u32 in registers, compensated value encoding.
// ---------------------------------------------------------------------------
__global__ __attribute__((amdgpu_flat_work_group_size(1024, 1024),
                          amdgpu_waves_per_eu(4, 4)))
void rnn_k(float* __restrict__ out,
           const float* __restrict__ init,
           const u32* __restrict__ wpkg,
           const u32* __restrict__ rowsp,
           const int* __restrict__ L1a){
  const int tid = threadIdx.x, b = blockIdx.x;
  u32 wk[CAP];
  #pragma unroll
  for (int k = 0; k < CAP; k++) wk[k] = wpkg[k * 1024 + tid];
  u32 rp = rowsp[tid];
  int rA = (int)(rp & 0xffffu), rB = (int)(rp >> 16);
  int L1 = L1a[tid];

  __shared__ float st[2048];
  st[tid]        = init[(size_t)b * 2048 + tid];
  st[tid + 1024] = init[(size_t)b * 2048 + tid + 1024];
  __syncthreads();
  const char* stb = (const char*)st;

  float* ob = out + (size_t)b * 1024 * 2048;
  float dA = __builtin_nontemporal_load(&ob[tid]);
  float dB = __builtin_nontemporal_load(&ob[tid + 1024]);
  for (int t = 0; t < 1024; t++){
    float* orow = ob + (size_t)t * 2048;
    const float* nrow = ob + (size_t)((t + 1) & 1023) * 2048;
    float dA2 = __builtin_nontemporal_load(&nrow[tid]);        // prefetch t+1
    float dB2 = __builtin_nontemporal_load(&nrow[tid + 1024]);
    float aAll = 0.f, aA = 0.f;
    #pragma unroll
    for (int k = 0; k < CAP; k++){
      u32 w = wk[k];
      float sv = *(const float*)(stb + (w & 0x1FFCu));
      float pv = __uint_as_float(w) * sv;
      aAll += pv;
      aA += (k < L1) ? pv : 0.0f;
    }
    float preA = aA + dA;                 // consume drive BEFORE barrier
    float preB = (aAll - aA) + dB;
    __syncthreads();                      // all st reads done
    float sA = tanh_fast(preA);
    float sB = tanh_fast(preB);
    st[rA] = sA; st[rB] = sB;
    __syncthreads();                      // new state visible
    __builtin_nontemporal_store(st[tid], &orow[tid]);          // coalesced
    __builtin_nontemporal_store(st[tid + 1024], &orow[tid + 1024]);
    dA = dA2; dB = dB2;
  }
}

// ---------------------------------------------------------------------------
extern "C" void kernel_launch(void* const* d_in, const int* in_sizes, int n_in,
                              void* d_out, int out_size, void* d_ws, size_t ws_size,
                              hipStream_t stream) {
  const float* x    = (const float*)d_in[0];
  const float* fb   = (const float*)d_in[1];
  const float* init = (const float*)d_in[2];
  const float* Wres = (const float*)d_in[3];
  const float* Win  = (const float*)d_in[4];
  const float* Wfb  = (const float*)d_in[5];
  float* out = (float*)d_out;

  char* w8 = (char*)d_ws;
  u16*  A_pack = (u16*)(w8);                       // 67108864 B
  u16*  B_pack = (u16*)(w8 + 67108864);            // 12582912 B
  u32*  wpk    = (u32*) (w8 + 79691776);           // 52*1024*4 = 212992
  int*  nnz    = (int*) (w8 + 79904768);           // 8192
  u32*  rowsp  = (u32*) (w8 + 79912960);           // 4096
  int*  L1a    = (int*) (w8 + 79917056);           // 4096
  int*  rowperm= (int*) (w8 + 79921152);           // 8192

  pack_a_k<<<32768, 256, 0, stream>>>(x, fb, A_pack);
  count_k<<<512, 256, 0, stream>>>(Wres, nnz);
  sort_k<<<1, 1024, 0, stream>>>(nnz, rowsp, L1a, rowperm);
  pack_b_k<<<4096, 256, 0, stream>>>(Win, Wfb, rowperm, B_pack);
  fill_k<<<256, 256, 0, stream>>>(Wres, rowsp, wpk);
  sched_k<<<16, 64, 0, stream>>>(wpk, rowsp, nnz);
  gemm_k<<<2048, 256, 0, stream>>>(A_pack, B_pack, out);
  rnn_k<<<16, 1024, 0, stream>>>(out, init, wpk, rowsp, L1a);
}

// Round 4
// 3581.665 us; speedup vs baseline: 1.1126x; 1.1126x over previous
//
#include <hip/hip_runtime.h>
#include <stdint.h>

typedef unsigned short u16;
typedef unsigned int   u32;
typedef __attribute__((ext_vector_type(8))) short short8;
typedef __attribute__((ext_vector_type(4))) float f32x4;

#define CAP   52
#define ROT   7

__device__ __forceinline__ u16 rne_bf16(float f){
  u32 u = __float_as_uint(f);
  u32 r = (u + 0x7fffu + ((u >> 16) & 1u)) >> 16;
  return (u16)r;
}
__device__ __forceinline__ float bf16_to_f(u16 h){
  return __uint_as_float(((u32)h) << 16);
}
__device__ __forceinline__ float tanh_fast(float x){
  float e = __expf(2.0f * x);
  return 1.0f - 2.0f / (e + 1.0f);
}

// ---------------------------------------------------------------------------
// A-pack: [xhi fbhi | xlo fblo], row m = b*1024+s, K=2048 bf16 bits
// ---------------------------------------------------------------------------
__global__ __launch_bounds__(256) void pack_a_k(const float* __restrict__ x,
                                                const float* __restrict__ fb,
                                                u16* __restrict__ A){
  int idx = blockIdx.x * 256 + threadIdx.x;          // 16384*512
  int m = idx >> 9, d = idx & 511;
  float xv = x[idx];
  float fv = fb[idx];
  u16 xh = rne_bf16(xv); u16 xl = rne_bf16(xv - bf16_to_f(xh));
  u16 fh = rne_bf16(fv); u16 fl = rne_bf16(fv - bf16_to_f(fh));
  size_t base = (size_t)m * 2048;
  A[base + d]        = xh;
  A[base + 512 + d]  = fh;
  A[base + 1024 + d] = xl;
  A[base + 1536 + d] = fl;
}

// ---------------------------------------------------------------------------
// B-pack with ROW PERMUTATION (row n of packed B = original row rowperm[n]).
// K=3072: [Winhi Wfbhi | Winhi Wfbhi | Winlo Wfblo]
// ---------------------------------------------------------------------------
__global__ __launch_bounds__(256) void pack_b_k(const float* __restrict__ Win,
                                                const float* __restrict__ Wfb,
                                                const int* __restrict__ rowperm,
                                                u16* __restrict__ Bm){
  int idx = blockIdx.x * 256 + threadIdx.x;          // 2048*512
  int n = idx >> 9, d = idx & 511;
  int row = rowperm[n];
  float iv = Win[(size_t)row * 512 + d];
  float fv = Wfb[(size_t)row * 512 + d];
  u16 ih = rne_bf16(iv); u16 il = rne_bf16(iv - bf16_to_f(ih));
  u16 fh = rne_bf16(fv); u16 fl = rne_bf16(fv - bf16_to_f(fh));
  size_t base = (size_t)n * 3072;
  Bm[base + d]        = ih;
  Bm[base + 512 + d]  = fh;
  Bm[base + 1024 + d] = ih;
  Bm[base + 1536 + d] = fh;
  Bm[base + 2048 + d] = il;
  Bm[base + 2560 + d] = fl;
}

// ---------------------------------------------------------------------------
// Drive GEMM: M=16384,N=2048,K=3072, 128x128 tile, plain coalesced stores.
// ---------------------------------------------------------------------------
#define GLDS(gp, lp) __builtin_amdgcn_global_load_lds( \
    (const __attribute__((address_space(1))) void*)(gp), \
    (__attribute__((address_space(3))) void*)(lp), 16, 0, 0)

__global__ __launch_bounds__(256) void gemm_k(const u16* __restrict__ A,
                                              const u16* __restrict__ Bm,
                                              float* __restrict__ C){
  __shared__ __align__(16) u16 As[128 * 32];
  __shared__ __align__(16) u16 Bs[128 * 32];
  const int tid = threadIdx.x;
  const int w = tid >> 6, l = tid & 63;
  const int bid = blockIdx.x;
  const int mt = bid >> 4, nt = bid & 15;
  const int m0 = mt * 128, n0 = nt * 128;
  const int srow = tid >> 2;
  const int scol = (tid & 3) * 8;
  const int wr = w & 1, wc = w >> 1;
  const int lhi = l >> 4, llo = l & 15;

  f32x4 acc[4][4];
  #pragma unroll
  for (int i = 0; i < 4; i++)
    #pragma unroll
    for (int j = 0; j < 4; j++)
      acc[i][j] = (f32x4){0.f, 0.f, 0.f, 0.f};

  for (int kt = 0; kt < 96; ++kt){
    int k = kt * 32;
    int keff = (k >= 2048) ? (k - 2048) : k;
    #pragma unroll
    for (int r = 0; r < 2; r++){
      const u16* ga = A  + (size_t)(m0 + r * 64 + srow) * 2048 + keff + scol;
      GLDS(ga, &As[r * 2048 + w * 512]);
      const u16* gb = Bm + (size_t)(n0 + r * 64 + srow) * 3072 + k + scol;
      GLDS(gb, &Bs[r * 2048 + w * 512]);
    }
    __syncthreads();
    short8 af[4], bf[4];
    #pragma unroll
    for (int i = 0; i < 4; i++){
      af[i] = *(const short8*)&As[(wr * 64 + i * 16 + llo) * 32 + lhi * 8];
      bf[i] = *(const short8*)&Bs[(wc * 64 + i * 16 + llo) * 32 + lhi * 8];
    }
    #pragma unroll
    for (int i = 0; i < 4; i++)
      #pragma unroll
      for (int j = 0; j < 4; j++)
        acc[i][j] = __builtin_amdgcn_mfma_f32_16x16x32_bf16(af[i], bf[j], acc[i][j], 0, 0, 0);
    __syncthreads();
  }
  #pragma unroll
  for (int i = 0; i < 4; i++)
    #pragma unroll
    for (int j = 0; j < 4; j++)
      #pragma unroll
      for (int rg = 0; rg < 4; rg++){
        int mr = m0 + wr * 64 + i * 16 + lhi * 4 + rg;
        int nc = n0 + wc * 64 + j * 16 + llo;
        C[(size_t)mr * 2048 + nc] = acc[i][j][rg];
      }
}

// ---------------------------------------------------------------------------
// count nnz per row (one wave per row)
// ---------------------------------------------------------------------------
__global__ __launch_bounds__(256) void count_k(const float* __restrict__ W,
                                               int* __restrict__ nnz){
  int gt = blockIdx.x * 256 + threadIdx.x;
  int row = gt >> 6, l = gt & 63;
  const float* wr = W + (size_t)row * 2048;
  int c = 0;
  for (int i = 0; i < 32; i++) c += (wr[i * 64 + l] != 0.0f) ? 1 : 0;
  for (int off = 32; off; off >>= 1) c += __shfl_down(c, off, 64);
  if (l == 0) nnz[row] = c;
}

// ---------------------------------------------------------------------------
// Counting-sort rows desc by nnz, pair p <-> 2047-p; emit rowperm for pack_b.
// ---------------------------------------------------------------------------
__global__ __launch_bounds__(1024) void sort_k(const int* __restrict__ nnz,
                                               u32* __restrict__ rowsp,
                                               int* __restrict__ L1a,
                                               int* __restrict__ rowperm){
  __shared__ int hist[64], off[64], cur[64];
  __shared__ int order[2048];
  int tid = threadIdx.x;
  if (tid < 64){ hist[tid] = 0; cur[tid] = 0; }
  __syncthreads();
  for (int r = tid; r < 2048; r += 1024){
    int b = nnz[r]; if (b > 63) b = 63;
    atomicAdd(&hist[b], 1);
  }
  __syncthreads();
  if (tid == 0){
    int run = 0;
    for (int b = 63; b >= 0; b--){ off[b] = run; run += hist[b]; }
  }
  __syncthreads();
  for (int r = tid; r < 2048; r += 1024){
    int b = nnz[r]; if (b > 63) b = 63;
    int pos = off[b] + atomicAdd(&cur[b], 1);
    order[pos] = r;
  }
  __syncthreads();
  int rA = order[tid], rB = order[2047 - tid];
  rowsp[tid] = (u32)rA | ((u32)rB << 16);
  L1a[tid] = nnz[rA];
  rowperm[tid] = rA;
  rowperm[tid + 1024] = rB;
}

// ---------------------------------------------------------------------------
// Fill RAW per-thread item words (slot-major): [0,L1)=rowA, [L1,..)=rowB.
// raw word = (f32 W bits rounded-to-nearest at 10-bit mantissa, bits 31:13)
//          | column index c in bits 10:0.  sched_k does the final address
//          assignment + compensation. Pads are generated by sched_k.
// ---------------------------------------------------------------------------
__global__ __launch_bounds__(256) void fill_k(const float* __restrict__ W,
                                              const u32* __restrict__ rowsp,
                                              u32* __restrict__ raw){
  int gt = blockIdx.x * 256 + threadIdx.x;
  int p = gt >> 6, l = gt & 63;
  u32 rp = rowsp[p];
  int rA = (int)(rp & 0xffffu), rB = (int)(rp >> 16);
  int base = 0;
  for (int h = 0; h < 2; h++){
    int row = h ? rB : rA;
    const float* wr = W + (size_t)row * 2048;
    int cnt = 0;
    for (int i = 0; i < 32; i++){
      int c = i * 64 + l;
      float v = wr[c];
      unsigned long long m = __ballot(v != 0.0f);
      int pre = __popcll(m & ((1ull << l) - 1ull));
      if (v != 0.0f){
        int s = base + cnt + pre;
        if (s < CAP){
          u32 u = __float_as_uint(v);
          u = ((u + 0x1000u) & 0xFFFFE000u) | (u32)c;
          raw[s * 1024 + p] = u;
        }
      }
      cnt += __popcll(m);
    }
    base += cnt;
  }
}

// ---------------------------------------------------------------------------
// PARITY-AWARE BANK SCHEDULER. One 64-lane wave per rnn wave (16 blocks).
// The rnn state has TWO LDS copies: copy0 (element j at dword j) read by
// EVEN slots, copy1 (rotated by ROT dwords) read by ODD slots. An item at
// slot s therefore hits bank c&31 (even) or (c+ROT)&31 (odd) -> two bank
// choices per item = slack the round-2/3 zero-slack matching lacked.
// Greedy first-fit with cap 2 per (slot,bank), relax when stuck. Item order
// is permuted only within segments ([0,L1)=rowA) -> rnn semantics intact.
// Output word = compensated (value,addr): low 13 bits = copy-relative byte
// addr, float(word) ~ weight (+/-1 ulp @ 10-bit mantissa).
// Pads (s>=nT) target underfull banks; their value ~ denormal ~ 0.
// ---------------------------------------------------------------------------
__global__ __launch_bounds__(64) void sched_k(const u32* __restrict__ raw,
                                              u32* __restrict__ wpk,
                                              const u32* __restrict__ rowsp,
                                              const int* __restrict__ nnz){
  __shared__ u32 pool[CAP * 64];                     // pool[j*64+lane]
  __shared__ int cnt[32];
  const int lane = threadIdx.x;
  const int p = blockIdx.x * 64 + lane;
  u32 rp = rowsp[p];
  int rA = (int)(rp & 0xffffu), rB = (int)(rp >> 16);
  int L1 = nnz[rA]; if (L1 > CAP) L1 = CAP;
  int nT = L1 + nnz[rB]; if (nT > CAP) nT = CAP;

  for (int k = 0; k < CAP; k++) pool[k * 64 + lane] = raw[k * 1024 + p];
  __syncthreads();

  unsigned long long used = 0ull;
  for (int s = 0; s < CAP; s++){
    if (lane < 32) cnt[lane] = 0;
    __syncthreads();
    const int par = s & 1;
    u32 word;
    if (s < nT){
      int lo = (s < L1) ? 0 : L1;
      int hi = (s < L1) ? L1 : nT;
      int chosen = -1;
      for (int capc = 2; chosen < 0; capc++){
        for (int j = lo; j < hi; j++){
          if (used & (1ull << j)) continue;
          int c = (int)(pool[j * 64 + lane] & 0x7FFu);
          int bk = (par ? (c + ROT) : c) & 31;
          int old = atomicAdd(&cnt[bk], 1);
          if (old < capc){ chosen = j; break; }
          atomicSub(&cnt[bk], 1);
        }
      }
      used |= 1ull << chosen;
      u32 r = pool[chosen * 64 + lane];
      u32 vb = r & 0xFFFFE000u;
      u32 c  = r & 0x7FFu;
      u32 ad = (u32)((par ? ((c + ROT) & 2047) : (int)c) << 2);
      word = ((vb - ad + 0x1000u) & 0xFFFFE000u) + ad;
    } else {
      int bsel = -1;
      for (int capc = 2; bsel < 0; capc++){
        for (int bb = 0; bb < 32; bb++){
          int bk = (bb + lane) & 31;
          int old = atomicAdd(&cnt[bk], 1);
          if (old < capc){ bsel = bk; break; }
          atomicSub(&cnt[bk], 1);
        }
      }
      word = (u32)bsel << 2;                         // value = denormal ~ 0
    }
    __syncthreads();
    wpk[s * 1024 + p] = word;
  }
}

// ---------------------------------------------------------------------------
// Recurrent kernel: 16 WGs (1 batch/CU), 1024 thr, 52 packed u32 in regs.
// State: 2 copies (copy1 rotated by ROT dwords) x 2 time-buffers = 32 KB.
// Slot k reads copy (k&1) via compile-time offset immediates -> no extra
// VALU. Writes go to all copies of the destination buffer (4 ds_write).
// ONE barrier per step (double-buffer removes the read/write WAR barrier).
// ---------------------------------------------------------------------------
__global__ __attribute__((amdgpu_flat_work_group_size(1024, 1024),
                          amdgpu_waves_per_eu(4, 4)))
void rnn_k(float* __restrict__ out,
           const float* __restrict__ init,
           const u32* __restrict__ wpkg,
           const u32* __restrict__ rowsp,
           const int* __restrict__ L1a){
  const int tid = threadIdx.x, b = blockIdx.x;
  u32 wk[CAP];
  #pragma unroll
  for (int k = 0; k < CAP; k++) wk[k] = wpkg[k * 1024 + tid];
  u32 rp = rowsp[tid];
  const int rA = (int)(rp & 0xffffu), rB = (int)(rp >> 16);
  const int L1 = L1a[tid];
  const int wA0 = rA << 2;
  const int wA1 = (((rA + ROT) & 2047) << 2) + 8192;
  const int wB0 = rB << 2;
  const int wB1 = (((rB + ROT) & 2047) << 2) + 8192;

  // [0,8K)=buf0.copy0  [8K,16K)=buf0.copy1  [16K,24K)=buf1.copy0  [24K,32K)=buf1.copy1
  __shared__ float st[8192];
  float i0 = init[(size_t)b * 2048 + tid];
  float i1 = init[(size_t)b * 2048 + tid + 1024];
  st[tid] = i0;
  st[tid + 1024] = i1;
  st[2048 + ((tid + ROT) & 2047)] = i0;
  st[2048 + ((tid + 1024 + ROT) & 2047)] = i1;
  __syncthreads();
  const char* stb = (const char*)st;
  char* stw = (char*)st;
  const int t4a = tid << 2, t4b = (tid + 1024) << 2;

  float* ob = out + (size_t)b * 1024 * 2048;
  float dA = __builtin_nontemporal_load(&ob[tid]);
  float dB = __builtin_nontemporal_load(&ob[tid + 1024]);

#define ESN_STEP(T, RD, WR) { \
    float* orow = ob + (size_t)(T) * 2048; \
    const float* nrow = ob + (size_t)(((T) + 1) & 1023) * 2048; \
    float dA2 = __builtin_nontemporal_load(&nrow[tid]); \
    float dB2 = __builtin_nontemporal_load(&nrow[tid + 1024]); \
    float aAll = 0.f, aA = 0.f; \
    _Pragma("unroll") \
    for (int k = 0; k < CAP; k++){ \
      u32 w = wk[k]; \
      float sv = *(const float*)(stb + (RD) + ((k & 1) ? 8192 : 0) + (w & 0x1FFCu)); \
      float pv = __uint_as_float(w) * sv; \
      aAll += pv; \
      aA += (k < L1) ? pv : 0.0f; \
    } \
    float preA = aA + dA; \
    float preB = (aAll - aA) + dB; \
    float sA = tanh_fast(preA); \
    float sB = tanh_fast(preB); \
    *(float*)(stw + (WR) + wA0) = sA; \
    *(float*)(stw + (WR) + wA1) = sA; \
    *(float*)(stw + (WR) + wB0) = sB; \
    *(float*)(stw + (WR) + wB1) = sB; \
    __syncthreads(); \
    __builtin_nontemporal_store(*(const float*)(stb + (WR) + t4a), &orow[tid]); \
    __builtin_nontemporal_store(*(const float*)(stb + (WR) + t4b), &orow[tid + 1024]); \
    dA = dA2; dB = dB2; \
  }

  for (int t = 0; t < 1024; t += 2){
    ESN_STEP(t, 0, 16384)
    ESN_STEP(t + 1, 16384, 0)
  }
#undef ESN_STEP
}

// ---------------------------------------------------------------------------
extern "C" void kernel_launch(void* const* d_in, const int* in_sizes, int n_in,
                              void* d_out, int out_size, void* d_ws, size_t ws_size,
                              hipStream_t stream) {
  const float* x    = (const float*)d_in[0];
  const float* fb   = (const float*)d_in[1];
  const float* init = (const float*)d_in[2];
  const float* Wres = (const float*)d_in[3];
  const float* Win  = (const float*)d_in[4];
  const float* Wfb  = (const float*)d_in[5];
  float* out = (float*)d_out;

  char* w8 = (char*)d_ws;
  u16*  A_pack = (u16*)(w8);                       // 67108864 B
  u16*  B_pack = (u16*)(w8 + 67108864);            // 12582912 B
  u32*  wpk    = (u32*) (w8 + 79691776);           // 52*1024*4 = 212992
  int*  nnz    = (int*) (w8 + 79904768);           // 8192
  u32*  rowsp  = (u32*) (w8 + 79912960);           // 4096
  int*  L1a    = (int*) (w8 + 79917056);           // 4096
  int*  rowperm= (int*) (w8 + 79921152);           // 8192
  u32*  raw    = (u32*) out;                       // dead before gemm writes out

  pack_a_k<<<32768, 256, 0, stream>>>(x, fb, A_pack);
  count_k<<<512, 256, 0, stream>>>(Wres, nnz);
  sort_k<<<1, 1024, 0, stream>>>(nnz, rowsp, L1a, rowperm);
  pack_b_k<<<4096, 256, 0, stream>>>(Win, Wfb, rowperm, B_pack);
  fill_k<<<256, 256, 0, stream>>>(Wres, rowsp, raw);
  sched_k<<<16, 64, 0, stream>>>(raw, wpk, rowsp, nnz);
  gemm_k<<<2048, 256, 0, stream>>>(A_pack, B_pack, out);
  rnn_k<<<16, 1024, 0, stream>>>(out, init, wpk, rowsp, L1a);
}